// Round 8
// baseline (153.425 us; speedup 1.0000x reference)
//
#include <hip/hip_runtime.h>

#define TT 200
#define NN 512
#define DD 4
#define HH 64
#define LL 32
#define SB 16                // sequences per block (fills MFMA M=16)
#define BPB (NN / SB)        // 32 blocks per batch
#define KP 72                // ushort pitch per h row (144B = 9*16B)
#define LOG2E 1.44269504088896340736f

typedef short bf16x8 __attribute__((ext_vector_type(8)));
typedef float f32x4 __attribute__((ext_vector_type(4)));

union U8 { unsigned short s[8]; unsigned u[4]; bf16x8 v; };

// f32 -> (hi, lo) bf16 limbs by truncation: x = hi + lo + err, |err| <= 2^-16 |x|
__device__ __forceinline__ void split2(float x, unsigned short& hi, unsigned short& lo) {
    unsigned u = __float_as_uint(x);
    hi = (unsigned short)(u >> 16);
    float lf = x - __uint_as_float(u & 0xffff0000u);
    lo = (unsigned short)(__float_as_uint(lf) >> 16);
}

__global__ __launch_bounds__(512, 1)
void gru_traj_kernel(const float* __restrict__ xg,    // (B,T,N,D)
                     const float* __restrict__ W_ih,  // (192,4)
                     const float* __restrict__ W_hh,  // (192,64)
                     const float* __restrict__ b_ih,  // (192,)
                     const float* __restrict__ b_hh,  // (192,)
                     const float* __restrict__ W_enc, // (32,64)
                     const float* __restrict__ b_enc, // (32,)
                     float* __restrict__ out)         // (B,N,32)
{
    __shared__ __align__(16) float xall[TT][SB][DD];          // 51.2 KB f32 x
    __shared__ __align__(16) unsigned short hhi[2][SB][KP];   // h hi-limbs (dbuf)
    __shared__ __align__(16) unsigned short hlo[2][SB][KP];   // h lo-limbs
    __shared__ __align__(16) float4 xchA[2][4][64];           // 8 KB partial exchange (R,Z)
    __shared__ __align__(16) float2 xchB[2][4][64];           // 4 KB partial exchange (N)
    __shared__ __align__(16) float hsf[SB][HH + 4];           // f32 h for epilogue

    const int tid = threadIdx.x;
    const int bid = blockIdx.x;
    const int b   = bid >> 5;                // bid / BPB
    const int n0  = (bid & (BPB - 1)) * SB;

    const int w  = tid >> 6;     // wave 0..7
    const int wq = w & 3;        // unit-tile: units 16wq..16wq+15
    const int wg = w >> 2;       // K-half AND row-half
    const int l  = tid & 63;
    const int lr = l & 15;       // A-row / B-col / C-col within tile
    const int lg = l >> 4;       // k-group (A/B), row-group (C)
    const int u  = 16 * wq + lr; // owned unit
    const int sb0 = lg * 4 + 2 * wg;  // first owned seq row

    // ---- prologue: preload whole x trajectory (f32) ----
    {
        float4* dst = reinterpret_cast<float4*>(&xall[0][0][0]);
        for (int f = tid; f < TT * 16; f += 512) {
            const int t = f >> 4, q = f & 15;
            dst[f] = *reinterpret_cast<const float4*>(
                xg + ((size_t)(b * TT + t) * NN + n0) * DD + q * 4);
        }
    }

    // ---- B fragments: my K-half (k = wg*32 + lg*8 + j), prescaled, bf16 hi/lo limbs ----
    const float sc[3] = { LOG2E, LOG2E, 2.0f * LOG2E };
    bf16x8 bh[3], bl[3];
    #pragma unroll
    for (int i = 0; i < 3; ++i) {
        const int g = i * 64 + u;
        const float* p = W_hh + g * HH + wg * 32 + lg * 8;
        U8 uh, ul;
        #pragma unroll
        for (int j = 0; j < 8; ++j) split2(p[j] * sc[i], uh.s[j], ul.s[j]);
        bh[i] = uh.v; bl[i] = ul.v;
    }
    // per-lane gate constants (unit u), prescaled
    float wih[3][4], cb[3];
    #pragma unroll
    for (int i = 0; i < 3; ++i) {
        const int g = i * 64 + u;
        wih[i][0] = W_ih[g * DD + 0] * sc[i]; wih[i][1] = W_ih[g * DD + 1] * sc[i];
        wih[i][2] = W_ih[g * DD + 2] * sc[i]; wih[i][3] = W_ih[g * DD + 3] * sc[i];
        cb[i] = (i < 2) ? (b_ih[g] + b_hh[g]) * sc[i] : b_ih[g] * sc[i];
    }
    const float bn = b_hh[2 * 64 + u] * sc[2];   // n-gate h-part bias (scaled)

    // ---- init: zero h limb buffers (h0 = 0) ----
    for (int idx = tid; idx < 2 * SB * KP / 2; idx += 512) {
        reinterpret_cast<unsigned*>(hhi)[idx] = 0u;
        reinterpret_cast<unsigned*>(hlo)[idx] = 0u;
    }
    float hreg[2] = {0.f, 0.f};   // h[sb0 + r][u], r = 0,1
    __syncthreads();

    const bool low = (__builtin_amdgcn_readfirstlane(wg) == 0);

    #pragma unroll 2
    for (int t = 0; t < TT; ++t) {
        const int cur = t & 1, nxt = cur ^ 1;

        // ---- A fragments: my K-half limb loads ----
        bf16x8 ah = *reinterpret_cast<const bf16x8*>(&hhi[cur][lr][wg * 32 + lg * 8]);
        bf16x8 al = *reinterpret_cast<const bf16x8*>(&hlo[cur][lr][wg * 32 + lg * 8]);

        // ---- gx for my 2 owned rows (f32 VALU, independent of MFMA chain) ----
        float4 x0 = *reinterpret_cast<const float4*>(&xall[t][sb0][0]);
        float4 x1 = *reinterpret_cast<const float4*>(&xall[t][sb0 + 1][0]);
        float gx0[3], gx1[3];
        #pragma unroll
        for (int i = 0; i < 3; ++i) {
            gx0[i] = fmaf(wih[i][0], x0.x, fmaf(wih[i][1], x0.y,
                     fmaf(wih[i][2], x0.z, fmaf(wih[i][3], x0.w, cb[i]))));
            gx1[i] = fmaf(wih[i][0], x1.x, fmaf(wih[i][1], x1.y,
                     fmaf(wih[i][2], x1.z, fmaf(wih[i][3], x1.w, cb[i]))));
        }

        // ---- 9 MFMAs: 3 independent depth-3 chains (K-half partials) ----
        const f32x4 z4 = {0.f, 0.f, 0.f, 0.f};
        f32x4 a0 = __builtin_amdgcn_mfma_f32_16x16x32_bf16(ah, bl[0], z4, 0,0,0);
        f32x4 a1 = __builtin_amdgcn_mfma_f32_16x16x32_bf16(ah, bl[1], z4, 0,0,0);
        f32x4 a2 = __builtin_amdgcn_mfma_f32_16x16x32_bf16(ah, bl[2], z4, 0,0,0);
        a0 = __builtin_amdgcn_mfma_f32_16x16x32_bf16(al, bh[0], a0, 0,0,0);
        a1 = __builtin_amdgcn_mfma_f32_16x16x32_bf16(al, bh[1], a1, 0,0,0);
        a2 = __builtin_amdgcn_mfma_f32_16x16x32_bf16(al, bh[2], a2, 0,0,0);
        a0 = __builtin_amdgcn_mfma_f32_16x16x32_bf16(ah, bh[0], a0, 0,0,0);
        a1 = __builtin_amdgcn_mfma_f32_16x16x32_bf16(ah, bh[1], a1, 0,0,0);
        a2 = __builtin_amdgcn_mfma_f32_16x16x32_bf16(ah, bh[2], a2, 0,0,0);

        // ---- send partner its rows' partials (compile-time component indices) ----
        if (low) {
            xchA[0][wq][l] = make_float4(a0[2], a0[3], a1[2], a1[3]);
            xchB[0][wq][l] = make_float2(a2[2], a2[3]);
        } else {
            xchA[1][wq][l] = make_float4(a0[0], a0[1], a1[0], a1[1]);
            xchB[1][wq][l] = make_float2(a2[0], a2[1]);
        }
        __syncthreads();   // bar1: partials visible

        float4 pA = xchA[wg ^ 1][wq][l];
        float2 pB = xchB[wg ^ 1][wq][l];
        float sR0, sR1, sZ0, sZ1, gh0, gh1;
        if (low) {
            sR0 = a0[0] + pA.x + gx0[0];  sR1 = a0[1] + pA.y + gx1[0];
            sZ0 = a1[0] + pA.z + gx0[1];  sZ1 = a1[1] + pA.w + gx1[1];
            gh0 = a2[0] + pB.x + bn;      gh1 = a2[1] + pB.y + bn;
        } else {
            sR0 = a0[2] + pA.x + gx0[0];  sR1 = a0[3] + pA.y + gx1[0];
            sZ0 = a1[2] + pA.z + gx0[1];  sZ1 = a1[3] + pA.w + gx1[1];
            gh0 = a2[2] + pB.x + bn;      gh1 = a2[3] + pB.y + bn;
        }

        // ---- gates (exp2 domain) + h update for 2 rows ----
        {
            float rg = __builtin_amdgcn_rcpf(1.0f + __builtin_amdgcn_exp2f(-sR0));
            float ez = __builtin_amdgcn_exp2f(-sZ0);
            float na = fmaf(rg, gh0, gx0[2]);
            na = fminf(fmaxf(na, -44.0f), 44.0f);
            float e  = __builtin_amdgcn_exp2f(-na);
            float nn = (1.0f - e) * __builtin_amdgcn_rcpf(1.0f + e);
            float z  = __builtin_amdgcn_rcpf(1.0f + ez);
            float hn = fmaf(z, hreg[0] - nn, nn);
            hreg[0] = hn;
            unsigned short hi, lo;
            split2(hn, hi, lo);
            hhi[nxt][sb0][u] = hi;
            hlo[nxt][sb0][u] = lo;
        }
        {
            float rg = __builtin_amdgcn_rcpf(1.0f + __builtin_amdgcn_exp2f(-sR1));
            float ez = __builtin_amdgcn_exp2f(-sZ1);
            float na = fmaf(rg, gh1, gx1[2]);
            na = fminf(fmaxf(na, -44.0f), 44.0f);
            float e  = __builtin_amdgcn_exp2f(-na);
            float nn = (1.0f - e) * __builtin_amdgcn_rcpf(1.0f + e);
            float z  = __builtin_amdgcn_rcpf(1.0f + ez);
            float hn = fmaf(z, hreg[1] - nn, nn);
            hreg[1] = hn;
            unsigned short hi, lo;
            split2(hn, hi, lo);
            hhi[nxt][sb0 + 1][u] = hi;
            hlo[nxt][sb0 + 1][u] = lo;
        }
        __syncthreads();   // bar2: h_{t+1} limbs visible
    }

    // ---- epilogue: out = h @ W_enc^T + b_enc (512 outputs, 1 per thread) ----
    hsf[sb0][u]     = hreg[0];
    hsf[sb0 + 1][u] = hreg[1];
    __syncthreads();
    {
        const int s = tid >> 5, li = tid & 31;
        float a = b_enc[li];
        #pragma unroll
        for (int k = 0; k < HH; ++k)
            a = fmaf(hsf[s][k], W_enc[li * HH + k], a);
        out[(bid * SB + s) * LL + li] = a;
    }
}

extern "C" void kernel_launch(void* const* d_in, const int* in_sizes, int n_in,
                              void* d_out, int out_size, void* d_ws, size_t ws_size,
                              hipStream_t stream) {
    const float* xg    = (const float*)d_in[0];
    const float* W_ih  = (const float*)d_in[1];
    const float* W_hh  = (const float*)d_in[2];
    const float* b_ih  = (const float*)d_in[3];
    const float* b_hh  = (const float*)d_in[4];
    const float* W_enc = (const float*)d_in[5];
    const float* b_enc = (const float*)d_in[6];
    float* out = (float*)d_out;

    dim3 grid(8 * BPB), block(512);   // 256 blocks x 512 threads -> 2 waves/SIMD
    hipLaunchKernelGGL(gru_traj_kernel, grid, block, 0, stream,
                       xg, W_ih, W_hh, b_ih, b_hh, W_enc, b_enc, out);
}